// Round 7
// baseline (896.421 us; speedup 1.0000x reference)
//
#include <hip/hip_runtime.h>
#include <hip/hip_bf16.h>
#include <cstdint>

#define DIM 768
#define HEADS 12
#define DH 64
#define MLP_DIM 3072
#define ROWS 8192   // 8*1024
#define SEQ 1024
#define PPAD 72     // attn P scratch row stride (elements)
#define ISTR 136    // bf16 epilogue image row stride (shorts)

typedef __attribute__((ext_vector_type(8))) short bf16x8;
typedef __attribute__((ext_vector_type(4))) float f32x4;

typedef __attribute__((address_space(1))) void GV;
typedef __attribute__((address_space(3))) void SV;

__device__ inline void async16(const void* g, void* l) {
  __builtin_amdgcn_global_load_lds((GV*)(void*)g, (SV*)l, 16, 0, 0);
}

__device__ inline unsigned short f2b(float f) {
  union { float f; uint32_t u; } v; v.f = f;
  uint32_t u = v.u;
  return (unsigned short)((u + 0x7fffu + ((u >> 16) & 1u)) >> 16);
}

// fast GELU (erf via Abramowitz-Stegun 7.1.25, |eps|<=2.5e-5)
__device__ inline float gelu_f(float v) {
  float x = v * 0.70710678118654752f;
  float ax = fabsf(x);
  float t = 1.f / (1.f + 0.47047f * ax);
  float poly = t * (0.3480242f + t * (-0.0958798f + t * 0.7478556f));
  float erfv = 1.f - poly * __expf(-ax * ax);
  erfv = copysignf(erfv, x);
  return 0.5f * v * (1.f + erfv);
}

// ---------------- transpose fp32 [K][N] -> bf16 [N][K] ----------------
__global__ __launch_bounds__(256) void transpose_k(const float* __restrict__ in,
                                                   unsigned short* __restrict__ out,
                                                   int K, int N) {
  __shared__ float t[32][33];
  int tx = threadIdx.x & 31, ty = threadIdx.x >> 5;
  int bn = blockIdx.x * 32, bk = blockIdx.y * 32;
#pragma unroll
  for (int i = ty; i < 32; i += 8) t[i][tx] = in[(size_t)(bk + i) * N + bn + tx];
  __syncthreads();
#pragma unroll
  for (int i = ty; i < 32; i += 8) out[(size_t)(bn + i) * K + bk + tx] = f2b(t[tx][i]);
}

// ---------------- layernorm fp32 -> bf16, one wave per row ----------------
__global__ __launch_bounds__(256) void ln_k(const float* __restrict__ x,
                                            const float* __restrict__ g,
                                            const float* __restrict__ b,
                                            unsigned short* __restrict__ h) {
  int wave = threadIdx.x >> 6, lane = threadIdx.x & 63;
  int row = blockIdx.x * 4 + wave;
  const float* xr = x + (size_t)row * DIM;
  float v[12];
  float s = 0.f;
#pragma unroll
  for (int j = 0; j < 12; ++j) { v[j] = xr[lane + j * 64]; s += v[j]; }
#pragma unroll
  for (int m = 1; m < 64; m <<= 1) s += __shfl_xor(s, m);
  float mu = s * (1.f / DIM);
  float vs = 0.f;
#pragma unroll
  for (int j = 0; j < 12; ++j) { float d = v[j] - mu; vs += d * d; }
#pragma unroll
  for (int m = 1; m < 64; m <<= 1) vs += __shfl_xor(vs, m);
  float rstd = rsqrtf(vs * (1.f / DIM) + 1e-5f);
  unsigned short* hr = h + (size_t)row * DIM;
#pragma unroll
  for (int j = 0; j < 12; ++j) {
    int i = lane + j * 64;
    hr[i] = f2b((v[j] - mu) * rstd * g[i] + b[i]);
  }
}

// ---- pipelined bf16 MFMA GEMM: global->VGPR prefetch -> ds_write -> MFMA ----
// Bt is [N][K]; BK=64; single LDS buffer, XOR-swizzled (chunk q of row r at q^(r&7)).
// TM=128 (256 thr, wave 64x64): MODE 0 QKV scatter, MODE 2 gelu->bf16
// TM=64  (256 thr, wave 32x64): MODE 1 acc+bias+resid->fp32
template <int MODE, int TM>
__global__ __launch_bounds__(256, 2) void gemm_k(
    const unsigned short* __restrict__ A, const unsigned short* __restrict__ Bt,
    int N, int K,
    const float* __restrict__ bias, const float* __restrict__ resid,
    float* __restrict__ outf, unsigned short* __restrict__ outb,
    unsigned short* __restrict__ Qb, unsigned short* __restrict__ Kb,
    unsigned short* __restrict__ Vt) {
  constexpr int MI = (TM == 128) ? 4 : 2;
  constexpr int ASH = TM * 64;                                  // A shorts
  constexpr int SMEMS = (TM == 128) ? 128 * ISTR : (ASH + 8192);
  __shared__ __align__(16) unsigned short smem[SMEMS];
  int tid = threadIdx.x;
  int wave = tid >> 6, lane = tid & 63, lrow = lane & 15, qd = lane >> 4;
  int ntn = N >> 7;
  int bm = (blockIdx.x / ntn) * TM;
  int bn = (blockIdx.x % ntn) << 7;
  int wm = (TM == 128) ? (wave >> 1) * 64 : (wave & 1) * 32;
  int wn = (TM == 128) ? (wave & 1) * 64 : (wave >> 1) * 64;

  f32x4 acc[MI][4];
#pragma unroll
  for (int i = 0; i < MI; ++i)
#pragma unroll
    for (int j = 0; j < 4; ++j) acc[i][j] = (f32x4){0.f, 0.f, 0.f, 0.f};

  // staging map: thread covers rows srow+32j, LDS chunk pos tid&7 holds
  // global chunk (tid&7)^(srow&7)
  int srow = tid >> 3;
  int c = (tid & 7) ^ (srow & 7);
  const char* gA = (const char*)(A + (size_t)(bm + srow) * K) + c * 16;
  const char* gB = (const char*)(Bt + (size_t)(bn + srow) * K) + c * 16;
  char* lA = (char*)smem + tid * 16;
  char* lB = (char*)smem + ASH * 2 + tid * 16;
  size_t rstep = (size_t)32 * K * 2;

  const unsigned short* As = smem;
  const unsigned short* Bs = smem + ASH;

  uint4 pa[TM / 32], pb[4];
  auto loadt = [&](int kt) {
    size_t ko = (size_t)kt * 128;
#pragma unroll
    for (int j = 0; j < TM / 32; ++j) pa[j] = *(const uint4*)(gA + ko + j * rstep);
#pragma unroll
    for (int j = 0; j < 4; ++j) pb[j] = *(const uint4*)(gB + ko + j * rstep);
  };

  int nk = K >> 6;
  loadt(0);
  for (int kt = 0; kt < nk; ++kt) {
    // write prefetched tile to LDS (vmcnt wait targets loads issued last iter)
#pragma unroll
    for (int j = 0; j < TM / 32; ++j) *(uint4*)(lA + j * 4096) = pa[j];
#pragma unroll
    for (int j = 0; j < 4; ++j) *(uint4*)(lB + j * 4096) = pb[j];
    __syncthreads();
    if (kt + 1 < nk) loadt(kt + 1);    // next tile in flight during MFMA
#pragma unroll
    for (int s = 0; s < 2; ++s) {
      int q = s * 4 + qd;
      bf16x8 af[MI], bfr[4];
#pragma unroll
      for (int i = 0; i < MI; ++i) {
        int r = wm + i * 16 + lrow;
        af[i] = *(const bf16x8*)(As + r * 64 + ((q ^ (r & 7)) << 3));
      }
#pragma unroll
      for (int i = 0; i < 4; ++i) {
        int r = wn + i * 16 + lrow;
        bfr[i] = *(const bf16x8*)(Bs + r * 64 + ((q ^ (r & 7)) << 3));
      }
#pragma unroll
      for (int mi = 0; mi < MI; ++mi)
#pragma unroll
        for (int ni = 0; ni < 4; ++ni)
          acc[mi][ni] = __builtin_amdgcn_mfma_f32_16x16x32_bf16(af[mi], bfr[ni], acc[mi][ni], 0, 0, 0);
    }
    __syncthreads();
  }

  if (MODE == 1) {
    // fp32 direct scalar epilogue (R4-proven)
#pragma unroll
    for (int mi = 0; mi < MI; ++mi)
#pragma unroll
      for (int ni = 0; ni < 4; ++ni)
#pragma unroll
        for (int r = 0; r < 4; ++r) {
          int row = bm + wm + mi * 16 + qd * 4 + r;
          int col = bn + wn + ni * 16 + lrow;
          float v = acc[mi][ni][r] + bias[col] + resid[(size_t)row * 768 + col];
          outf[(size_t)row * 768 + col] = v;
        }
  } else if (MODE == 2) {
    // bf16 image 128x128 with gelu(acc+bias), vectorized store
    unsigned short* img = smem;
#pragma unroll
    for (int mi = 0; mi < MI; ++mi)
#pragma unroll
      for (int ni = 0; ni < 4; ++ni)
#pragma unroll
        for (int r = 0; r < 4; ++r) {
          int lc = wn + ni * 16 + lrow;
          float v = acc[mi][ni][r] + bias[bn + lc];
          img[(wm + mi * 16 + qd * 4 + r) * ISTR + lc] = f2b(gelu_f(v));
        }
    __syncthreads();
#pragma unroll
    for (int p = 0; p < 2; ++p) {
      int lr = p * 64 + (tid >> 2);
      int cs = (tid & 3) * 32;
      const unsigned short* src = img + lr * ISTR + cs;
      unsigned short* dst = outb + (size_t)(bm + lr) * MLP_DIM + bn + cs;
#pragma unroll
      for (int k = 0; k < 4; ++k) *(uint4*)(dst + k * 8) = *(const uint4*)(src + k * 8);
    }
  } else {
    // MODE 0: QKV scatter; tile lies entirely in Q, K, or V (128 | 768)
    int which = bn / 768;
    int rem_base = bn - which * 768;
    unsigned short* img = smem;
    if (which < 2) {
#pragma unroll
      for (int mi = 0; mi < MI; ++mi)
#pragma unroll
        for (int ni = 0; ni < 4; ++ni)
#pragma unroll
          for (int r = 0; r < 4; ++r) {
            float v = acc[mi][ni][r];
            if (which == 0) v *= 0.125f;
            img[(wm + mi * 16 + qd * 4 + r) * ISTR + wn + ni * 16 + lrow] = f2b(v);
          }
      __syncthreads();
      int lr = tid >> 1, hseg = tid & 1;
      int hh = rem_base / 64 + hseg;
      int b = (bm + lr) >> 10, n = (bm + lr) & 1023;
      size_t bh = (size_t)(b * HEADS + hh);
      const unsigned short* src = img + lr * ISTR + hseg * 64;
      unsigned short* dst = (which == 0 ? Qb : Kb) + (bh * SEQ + n) * DH;
      if (which == 0) {
#pragma unroll
        for (int j = 0; j < 8; ++j) *(uint4*)(dst + j * 8) = *(const uint4*)(src + j * 8);
      } else {
        int nx = n & 7;
#pragma unroll
        for (int j = 0; j < 8; ++j) *(uint4*)(dst + ((j ^ nx) * 8)) = *(const uint4*)(src + j * 8);
      }
    } else {
      // V: write image transposed (rows become dh, cols become keys)
#pragma unroll
      for (int mi = 0; mi < MI; ++mi)
#pragma unroll
        for (int ni = 0; ni < 4; ++ni) {
          int lc = wn + ni * 16 + lrow;
          int rbase = wm + mi * 16 + qd * 4;
          uint2 pk;
          pk.x = (uint32_t)f2b(acc[mi][ni][0]) | ((uint32_t)f2b(acc[mi][ni][1]) << 16);
          pk.y = (uint32_t)f2b(acc[mi][ni][2]) | ((uint32_t)f2b(acc[mi][ni][3]) << 16);
          *(uint2*)(img + lc * ISTR + rbase) = pk;
        }
      __syncthreads();
      int d = tid >> 1, nh = tid & 1;          // d: 0..127 (2 heads x 64 dh)
      int hh = rem_base / 64 + (d >> 6);
      int dhl = d & 63;
      int b = bm >> 10;
      size_t bh = (size_t)(b * HEADS + hh);
      const unsigned short* src = img + d * ISTR + nh * 64;
      unsigned short* dst = Vt + (bh * DH + dhl) * SEQ + (bm & 1023) + nh * 64;
      int dx = dhl & 7;
#pragma unroll
      for (int j = 0; j < 8; ++j) *(uint4*)(dst + ((j ^ dx) * 8)) = *(const uint4*)(src + j * 8);
    }
  }
}

// ---------------- flash attention v2 (round-4, unchanged) ----------------
__global__ __launch_bounds__(256, 3) void attn_k(const unsigned short* __restrict__ Qb,
                                                 const unsigned short* __restrict__ Kb,
                                                 const unsigned short* __restrict__ Vt,
                                                 unsigned short* __restrict__ o) {
  __shared__ __align__(16) unsigned short Ks[2][64 * 64];
  __shared__ __align__(16) unsigned short Vs[2][64 * 64];
  __shared__ __align__(16) unsigned short Pa[4][32 * PPAD];
  int tid = threadIdx.x;
  int wave = tid >> 6, lane = tid & 63;
  int lrow = lane & 15, qd = lane >> 4;
  int bh = blockIdx.x % 96;
  int qt = blockIdx.x / 96;
  int b = bh / HEADS, hh = bh % HEADS;
  const unsigned short* Qh = Qb + (size_t)bh * SEQ * DH;
  const char* Kh = (const char*)(Kb + (size_t)bh * SEQ * DH);
  const char* Vh = (const char*)(Vt + (size_t)bh * DH * SEQ);
  int qw = qt * 128 + wave * 32;

  bf16x8 qf[2][2];
#pragma unroll
  for (int qs = 0; qs < 2; ++qs)
#pragma unroll
    for (int hf = 0; hf < 2; ++hf)
      qf[qs][hf] = *(const bf16x8*)(Qh + (qw + qs * 16 + lrow) * DH + hf * 32 + qd * 8);

  f32x4 oacc[2][4];
#pragma unroll
  for (int qs = 0; qs < 2; ++qs)
#pragma unroll
    for (int d = 0; d < 4; ++d) oacc[qs][d] = (f32x4){0.f, 0.f, 0.f, 0.f};
  float li[2] = {0.f, 0.f};
  unsigned short* Pw = Pa[wave];

  auto stage = [&](int t, int buf) {
    const char* kbase = Kh + (size_t)t * 8192;
    char* kd = (char*)Ks[buf];
    async16(kbase + tid * 16, kd + tid * 16);
    async16(kbase + 4096 + tid * 16, kd + 4096 + tid * 16);
    const char* vbase = Vh + (size_t)t * 128;
    char* vd = (char*)Vs[buf];
    async16(vbase + (size_t)(tid >> 3) * 2048 + (tid & 7) * 16, vd + tid * 16);
    async16(vbase + (size_t)((tid >> 3) + 32) * 2048 + (tid & 7) * 16, vd + 4096 + tid * 16);
  };

  stage(0, 0);
  for (int t = 0; t < 16; ++t) {
    asm volatile("s_waitcnt vmcnt(0)" ::: "memory");
    __syncthreads();
    if (t < 15) stage(t + 1, (t + 1) & 1);
    const unsigned short* Kst = Ks[t & 1];
    const unsigned short* Vst = Vs[t & 1];

    f32x4 st[4][2];
#pragma unroll
    for (int kt = 0; kt < 4; ++kt) {
      int krow = kt * 16 + lrow;
      int ksw = krow & 7;
      const unsigned short* Kr = Kst + krow * 64;
      bf16x8 k0 = *(const bf16x8*)(Kr + ((qd ^ ksw) << 3));
      bf16x8 k1 = *(const bf16x8*)(Kr + (((qd + 4) ^ ksw) << 3));
#pragma unroll
      for (int qs = 0; qs < 2; ++qs) {
        f32x4 z = (f32x4){0.f, 0.f, 0.f, 0.f};
        z = __builtin_amdgcn_mfma_f32_16x16x32_bf16(k0, qf[qs][0], z, 0, 0, 0);
        z = __builtin_amdgcn_mfma_f32_16x16x32_bf16(k1, qf[qs][1], z, 0, 0, 0);
        st[kt][qs] = z;
      }
    }

#pragma unroll
    for (int kt = 0; kt < 4; ++kt)
#pragma unroll
      for (int qs = 0; qs < 2; ++qs) {
        float p0 = __expf(st[kt][qs][0]);
        float p1 = __expf(st[kt][qs][1]);
        float p2 = __expf(st[kt][qs][2]);
        float p3 = __expf(st[kt][qs][3]);
        li[qs] += (p0 + p1) + (p2 + p3);
        uint2 pk;
        pk.x = (uint32_t)f2b(p0) | ((uint32_t)f2b(p1) << 16);
        pk.y = (uint32_t)f2b(p2) | ((uint32_t)f2b(p3) << 16);
        *(uint2*)(Pw + (qs * 16 + lrow) * PPAD + kt * 16 + qd * 4) = pk;
      }
    asm volatile("s_waitcnt lgkmcnt(0)" ::: "memory");

    bf16x8 ap[2][2];
#pragma unroll
    for (int qs = 0; qs < 2; ++qs)
#pragma unroll
      for (int kh = 0; kh < 2; ++kh)
        ap[qs][kh] = *(const bf16x8*)(Pw + (qs * 16 + lrow) * PPAD + kh * 32 + qd * 8);

#pragma unroll
    for (int ds = 0; ds < 4; ++ds) {
      int vrow = ds * 16 + lrow;
      int vsw = vrow & 7;
      const unsigned short* Vr = Vst + vrow * 64;
      bf16x8 v0 = *(const bf16x8*)(Vr + ((qd ^ vsw) << 3));
      bf16x8 v1 = *(const bf16x8*)(Vr + (((4 + qd) ^ vsw) << 3));
#pragma unroll
      for (int qs = 0; qs < 2; ++qs) {
        oacc[qs][ds] = __builtin_amdgcn_mfma_f32_16x16x32_bf16(ap[qs][0], v0, oacc[qs][ds], 0, 0, 0);
        oacc[qs][ds] = __builtin_amdgcn_mfma_f32_16x16x32_bf16(ap[qs][1], v1, oacc[qs][ds], 0, 0, 0);
      }
    }
  }

#pragma unroll
  for (int qs = 0; qs < 2; ++qs) {
    li[qs] += __shfl_xor(li[qs], 16);
    li[qs] += __shfl_xor(li[qs], 32);
  }

#pragma unroll
  for (int qs = 0; qs < 2; ++qs)
#pragma unroll
    for (int r = 0; r < 4; ++r) {
      float inv = 1.f / __shfl(li[qs], qd * 4 + r);
      int n = qw + qs * 16 + qd * 4 + r;
#pragma unroll
      for (int ds = 0; ds < 4; ++ds) {
        int dh = ds * 16 + lrow;
        o[((size_t)(b * SEQ + n)) * DIM + hh * DH + dh] = f2b(oacc[qs][ds][r] * inv);
      }
    }
}

extern "C" void kernel_launch(void* const* d_in, const int* in_sizes, int n_in,
                              void* d_out, int out_size, void* d_ws, size_t ws_size,
                              hipStream_t stream) {
  const float* x     = (const float*)d_in[0];
  const float* ln1_g = (const float*)d_in[1];
  const float* ln1_b = (const float*)d_in[2];
  const float* w_qkv = (const float*)d_in[3];
  const float* w_out = (const float*)d_in[4];
  const float* b_out = (const float*)d_in[5];
  const float* ln2_g = (const float*)d_in[6];
  const float* ln2_b = (const float*)d_in[7];
  const float* w1    = (const float*)d_in[8];
  const float* b1    = (const float*)d_in[9];
  const float* w2    = (const float*)d_in[10];
  const float* b2    = (const float*)d_in[11];

  char* ws = (char*)d_ws;
  unsigned short* wqkvT = (unsigned short*)(ws + 0);
  unsigned short* woutT = (unsigned short*)(ws + 3538944);
  unsigned short* w1T   = (unsigned short*)(ws + 4718592);
  unsigned short* w2T   = (unsigned short*)(ws + 9437184);
  float*          x2    = (float*)(ws + 14155776);
  unsigned short* h     = (unsigned short*)(ws + 39321600);
  char* big = ws + 51904512;
  unsigned short* Qb = (unsigned short*)(big);
  unsigned short* Kb = (unsigned short*)(big + 12582912);
  unsigned short* Vt = (unsigned short*)(big + 25165824);
  unsigned short* ob = (unsigned short*)(big + 37748736);
  unsigned short* am = (unsigned short*)(big);

  transpose_k<<<dim3(72, 24), 256, 0, stream>>>(w_qkv, wqkvT, 768, 2304);
  transpose_k<<<dim3(24, 24), 256, 0, stream>>>(w_out, woutT, 768, 768);
  transpose_k<<<dim3(96, 24), 256, 0, stream>>>(w1, w1T, 768, 3072);
  transpose_k<<<dim3(24, 96), 256, 0, stream>>>(w2, w2T, 3072, 768);

  ln_k<<<2048, 256, 0, stream>>>(x, ln1_g, ln1_b, h);
  gemm_k<0, 128><<<64 * 18, 256, 0, stream>>>(h, wqkvT, 2304, 768,
                                              nullptr, nullptr, nullptr, nullptr, Qb, Kb, Vt);
  attn_k<<<768, 256, 0, stream>>>(Qb, Kb, Vt, ob);
  gemm_k<1, 64><<<128 * 6, 256, 0, stream>>>(ob, woutT, 768, 768,
                                             b_out, x, x2, nullptr, nullptr, nullptr, nullptr);
  ln_k<<<2048, 256, 0, stream>>>(x2, ln2_g, ln2_b, h);
  gemm_k<2, 128><<<64 * 24, 256, 0, stream>>>(h, w1T, 3072, 768,
                                              b1, nullptr, nullptr, am, nullptr, nullptr, nullptr);
  gemm_k<1, 64><<<128 * 6, 256, 0, stream>>>(am, w2T, 768, 3072,
                                             b2, x2, (float*)d_out, nullptr, nullptr, nullptr, nullptr);
}

// Round 8
// 363.272 us; speedup vs baseline: 2.4676x; 2.4676x over previous
//
#include <hip/hip_runtime.h>
#include <hip/hip_bf16.h>
#include <cstdint>

#define DIM 768
#define HEADS 12
#define DH 64
#define MLP_DIM 3072
#define ROWS 8192   // 8*1024
#define SEQ 1024
#define PPAD 72     // attn P scratch row stride (elements)
#define ISTR 136    // bf16 epilogue image row stride (shorts)

typedef __attribute__((ext_vector_type(8))) short bf16x8;
typedef __attribute__((ext_vector_type(4))) float f32x4;

typedef __attribute__((address_space(1))) void GV;
typedef __attribute__((address_space(3))) void SV;

__device__ inline void async16(const void* g, void* l) {
  __builtin_amdgcn_global_load_lds((GV*)(void*)g, (SV*)l, 16, 0, 0);
}

__device__ inline unsigned short f2b(float f) {
  union { float f; uint32_t u; } v; v.f = f;
  uint32_t u = v.u;
  return (unsigned short)((u + 0x7fffu + ((u >> 16) & 1u)) >> 16);
}

// fast GELU (erf via Abramowitz-Stegun 7.1.25, |eps|<=2.5e-5)
__device__ inline float gelu_f(float v) {
  float x = v * 0.70710678118654752f;
  float ax = fabsf(x);
  float t = 1.f / (1.f + 0.47047f * ax);
  float poly = t * (0.3480242f + t * (-0.0958798f + t * 0.7478556f));
  float erfv = 1.f - poly * __expf(-ax * ax);
  erfv = copysignf(erfv, x);
  return 0.5f * v * (1.f + erfv);
}

// ---------------- transpose fp32 [K][N] -> bf16 [N][K] ----------------
__global__ __launch_bounds__(256) void transpose_k(const float* __restrict__ in,
                                                   unsigned short* __restrict__ out,
                                                   int K, int N) {
  __shared__ float t[32][33];
  int tx = threadIdx.x & 31, ty = threadIdx.x >> 5;
  int bn = blockIdx.x * 32, bk = blockIdx.y * 32;
#pragma unroll
  for (int i = ty; i < 32; i += 8) t[i][tx] = in[(size_t)(bk + i) * N + bn + tx];
  __syncthreads();
#pragma unroll
  for (int i = ty; i < 32; i += 8) out[(size_t)(bn + i) * K + bk + tx] = f2b(t[tx][i]);
}

// ---------------- layernorm fp32 -> bf16, one wave per row ----------------
__global__ __launch_bounds__(256) void ln_k(const float* __restrict__ x,
                                            const float* __restrict__ g,
                                            const float* __restrict__ b,
                                            unsigned short* __restrict__ h) {
  int wave = threadIdx.x >> 6, lane = threadIdx.x & 63;
  int row = blockIdx.x * 4 + wave;
  const float* xr = x + (size_t)row * DIM;
  float v[12];
  float s = 0.f;
#pragma unroll
  for (int j = 0; j < 12; ++j) { v[j] = xr[lane + j * 64]; s += v[j]; }
#pragma unroll
  for (int m = 1; m < 64; m <<= 1) s += __shfl_xor(s, m);
  float mu = s * (1.f / DIM);
  float vs = 0.f;
#pragma unroll
  for (int j = 0; j < 12; ++j) { float d = v[j] - mu; vs += d * d; }
#pragma unroll
  for (int m = 1; m < 64; m <<= 1) vs += __shfl_xor(vs, m);
  float rstd = rsqrtf(vs * (1.f / DIM) + 1e-5f);
  unsigned short* hr = h + (size_t)row * DIM;
#pragma unroll
  for (int j = 0; j < 12; ++j) {
    int i = lane + j * 64;
    hr[i] = f2b((v[j] - mu) * rstd * g[i] + b[i]);
  }
}

// ---- pipelined bf16 MFMA GEMM: global->VGPR prefetch (named regs) -> LDS ----
// Bt is [N][K]; BK=64; single LDS buffer, XOR-swizzled (chunk q of row r at q^(r&7)).
// TM=128 (wave 64x64): MODE 0 QKV scatter (scalar, R3-proven), MODE 2 gelu->bf16 (vec image)
// TM=64  (wave 32x64): MODE 1 acc+bias+resid->fp32 (scalar, R3-proven)
template <int MODE, int TM>
__global__ __launch_bounds__(256, 2) void gemm_k(
    const unsigned short* __restrict__ A, const unsigned short* __restrict__ Bt,
    int N, int K,
    const float* __restrict__ bias, const float* __restrict__ resid,
    float* __restrict__ outf, unsigned short* __restrict__ outb,
    unsigned short* __restrict__ Qb, unsigned short* __restrict__ Kb,
    unsigned short* __restrict__ Vt) {
  constexpr int MI = (TM == 128) ? 4 : 2;
  constexpr int ASH = TM * 64;   // A shorts
  constexpr int SMEMS = (TM == 128) ? ((MODE == 2) ? 128 * ISTR : 16384) : 12288;
  __shared__ __align__(16) unsigned short smem[SMEMS];
  int tid = threadIdx.x;
  int wave = tid >> 6, lane = tid & 63, lrow = lane & 15, qd = lane >> 4;
  int ntn = N >> 7;
  int bm = (blockIdx.x / ntn) * TM;
  int bn = (blockIdx.x % ntn) << 7;
  int wm = (TM == 128) ? (wave >> 1) * 64 : (wave & 1) * 32;
  int wn = (TM == 128) ? (wave & 1) * 64 : (wave >> 1) * 64;

  f32x4 acc[MI][4];
#pragma unroll
  for (int i = 0; i < MI; ++i)
#pragma unroll
    for (int j = 0; j < 4; ++j) acc[i][j] = (f32x4){0.f, 0.f, 0.f, 0.f};

  // staging map: thread covers rows srow+32j; LDS chunk pos tid&7 holds
  // global chunk (tid&7)^(srow&7)
  int srow = tid >> 3;
  int c = (tid & 7) ^ (srow & 7);
  const char* gA = (const char*)(A + (size_t)(bm + srow) * K) + c * 16;
  const char* gB = (const char*)(Bt + (size_t)(bn + srow) * K) + c * 16;
  char* lA = (char*)smem + tid * 16;
  char* lB = (char*)smem + ASH * 2 + tid * 16;
  size_t rstep = (size_t)32 * K * 2;

  const unsigned short* As = smem;
  const unsigned short* Bs = smem + ASH;

  // prefetch regs: named scalars only (nothing address-taken -> no scratch)
  uint4 pa0, pa1, pa2, pa3, pb0, pb1, pb2, pb3;
  pa0 = *(const uint4*)(gA);
  pa1 = *(const uint4*)(gA + rstep);
  if constexpr (TM == 128) {
    pa2 = *(const uint4*)(gA + 2 * rstep);
    pa3 = *(const uint4*)(gA + 3 * rstep);
  }
  pb0 = *(const uint4*)(gB);
  pb1 = *(const uint4*)(gB + rstep);
  pb2 = *(const uint4*)(gB + 2 * rstep);
  pb3 = *(const uint4*)(gB + 3 * rstep);

  int nk = K >> 6;
  for (int kt = 0; kt < nk; ++kt) {
    // commit prefetched tile to LDS (vmcnt waits on loads issued a full
    // MFMA-phase ago)
    *(uint4*)(lA) = pa0;
    *(uint4*)(lA + 4096) = pa1;
    if constexpr (TM == 128) {
      *(uint4*)(lA + 8192) = pa2;
      *(uint4*)(lA + 12288) = pa3;
    }
    *(uint4*)(lB) = pb0;
    *(uint4*)(lB + 4096) = pb1;
    *(uint4*)(lB + 8192) = pb2;
    *(uint4*)(lB + 12288) = pb3;
    __syncthreads();
    if (kt + 1 < nk) {
      size_t k2 = (size_t)(kt + 1) * 128;
      pa0 = *(const uint4*)(gA + k2);
      pa1 = *(const uint4*)(gA + k2 + rstep);
      if constexpr (TM == 128) {
        pa2 = *(const uint4*)(gA + k2 + 2 * rstep);
        pa3 = *(const uint4*)(gA + k2 + 3 * rstep);
      }
      pb0 = *(const uint4*)(gB + k2);
      pb1 = *(const uint4*)(gB + k2 + rstep);
      pb2 = *(const uint4*)(gB + k2 + 2 * rstep);
      pb3 = *(const uint4*)(gB + k2 + 3 * rstep);
    }
#pragma unroll
    for (int s = 0; s < 2; ++s) {
      int q = s * 4 + qd;
      bf16x8 af[MI], bfr[4];
#pragma unroll
      for (int i = 0; i < MI; ++i) {
        int r = wm + i * 16 + lrow;
        af[i] = *(const bf16x8*)(As + r * 64 + ((q ^ (r & 7)) << 3));
      }
#pragma unroll
      for (int i = 0; i < 4; ++i) {
        int r = wn + i * 16 + lrow;
        bfr[i] = *(const bf16x8*)(Bs + r * 64 + ((q ^ (r & 7)) << 3));
      }
#pragma unroll
      for (int mi = 0; mi < MI; ++mi)
#pragma unroll
        for (int ni = 0; ni < 4; ++ni)
          acc[mi][ni] = __builtin_amdgcn_mfma_f32_16x16x32_bf16(af[mi], bfr[ni], acc[mi][ni], 0, 0, 0);
    }
    __syncthreads();
  }

  if (MODE == 1) {
    // scalar epilogue (R3-proven)
#pragma unroll
    for (int mi = 0; mi < MI; ++mi)
#pragma unroll
      for (int ni = 0; ni < 4; ++ni)
#pragma unroll
        for (int r = 0; r < 4; ++r) {
          int row = bm + wm + mi * 16 + qd * 4 + r;
          int col = bn + wn + ni * 16 + lrow;
          float v = acc[mi][ni][r] + bias[col] + resid[(size_t)row * 768 + col];
          outf[(size_t)row * 768 + col] = v;
        }
  } else if (MODE == 2) {
    // bf16 image 128x128 with gelu(acc+bias), vectorized store (proven 85->74)
    unsigned short* img = smem;
#pragma unroll
    for (int mi = 0; mi < MI; ++mi)
#pragma unroll
      for (int ni = 0; ni < 4; ++ni)
#pragma unroll
        for (int r = 0; r < 4; ++r) {
          int lc = wn + ni * 16 + lrow;
          float v = acc[mi][ni][r] + bias[bn + lc];
          img[(wm + mi * 16 + qd * 4 + r) * ISTR + lc] = f2b(gelu_f(v));
        }
    __syncthreads();
#pragma unroll
    for (int p = 0; p < 2; ++p) {
      int lr = p * 64 + (tid >> 2);
      int cs = (tid & 3) * 32;
      const unsigned short* src = img + lr * ISTR + cs;
      unsigned short* dst = outb + (size_t)(bm + lr) * MLP_DIM + bn + cs;
#pragma unroll
      for (int k = 0; k < 4; ++k) *(uint4*)(dst + k * 8) = *(const uint4*)(src + k * 8);
    }
  } else {
    // MODE 0: scalar QKV scatter (R3-proven); Q pre-scaled, K/V swizzled
#pragma unroll
    for (int mi = 0; mi < MI; ++mi)
#pragma unroll
      for (int ni = 0; ni < 4; ++ni)
#pragma unroll
        for (int r = 0; r < 4; ++r) {
          int row = bm + wm + mi * 16 + qd * 4 + r;
          int col = bn + wn + ni * 16 + lrow;
          float v = acc[mi][ni][r];
          int which = col / 768;
          int rem = col - which * 768;
          int hh = rem >> 6, dh = rem & 63;
          int bb = row >> 10, n = row & 1023;
          size_t bh = (size_t)(bb * HEADS + hh);
          if (which == 0) {
            Qb[(bh * SEQ + n) * DH + dh] = f2b(v * 0.125f);
          } else if (which == 1) {
            Kb[(bh * SEQ + n) * DH + (((dh >> 3) ^ (n & 7)) << 3) + (dh & 7)] = f2b(v);
          } else {
            Vt[(bh * DH + dh) * SEQ + (n & ~63) +
               ((((n >> 3) & 7) ^ (dh & 7)) << 3) + (n & 7)] = f2b(v);
          }
        }
  }
}

// ---------------- flash attention v2 (round-3-proposal, unchanged) ---------
__global__ __launch_bounds__(256, 3) void attn_k(const unsigned short* __restrict__ Qb,
                                                 const unsigned short* __restrict__ Kb,
                                                 const unsigned short* __restrict__ Vt,
                                                 unsigned short* __restrict__ o) {
  __shared__ __align__(16) unsigned short Ks[2][64 * 64];
  __shared__ __align__(16) unsigned short Vs[2][64 * 64];
  __shared__ __align__(16) unsigned short Pa[4][32 * PPAD];
  int tid = threadIdx.x;
  int wave = tid >> 6, lane = tid & 63;
  int lrow = lane & 15, qd = lane >> 4;
  int bh = blockIdx.x % 96;
  int qt = blockIdx.x / 96;
  int b = bh / HEADS, hh = bh % HEADS;
  const unsigned short* Qh = Qb + (size_t)bh * SEQ * DH;
  const char* Kh = (const char*)(Kb + (size_t)bh * SEQ * DH);
  const char* Vh = (const char*)(Vt + (size_t)bh * DH * SEQ);
  int qw = qt * 128 + wave * 32;

  bf16x8 qf[2][2];
#pragma unroll
  for (int qs = 0; qs < 2; ++qs)
#pragma unroll
    for (int hf = 0; hf < 2; ++hf)
      qf[qs][hf] = *(const bf16x8*)(Qh + (qw + qs * 16 + lrow) * DH + hf * 32 + qd * 8);

  f32x4 oacc[2][4];
#pragma unroll
  for (int qs = 0; qs < 2; ++qs)
#pragma unroll
    for (int d = 0; d < 4; ++d) oacc[qs][d] = (f32x4){0.f, 0.f, 0.f, 0.f};
  float li[2] = {0.f, 0.f};
  unsigned short* Pw = Pa[wave];

  auto stage = [&](int t, int buf) {
    const char* kbase = Kh + (size_t)t * 8192;
    char* kd = (char*)Ks[buf];
    async16(kbase + tid * 16, kd + tid * 16);
    async16(kbase + 4096 + tid * 16, kd + 4096 + tid * 16);
    const char* vbase = Vh + (size_t)t * 128;
    char* vd = (char*)Vs[buf];
    async16(vbase + (size_t)(tid >> 3) * 2048 + (tid & 7) * 16, vd + tid * 16);
    async16(vbase + (size_t)((tid >> 3) + 32) * 2048 + (tid & 7) * 16, vd + 4096 + tid * 16);
  };

  stage(0, 0);
  for (int t = 0; t < 16; ++t) {
    asm volatile("s_waitcnt vmcnt(0)" ::: "memory");
    __syncthreads();
    if (t < 15) stage(t + 1, (t + 1) & 1);
    const unsigned short* Kst = Ks[t & 1];
    const unsigned short* Vst = Vs[t & 1];

    f32x4 st[4][2];
#pragma unroll
    for (int kt = 0; kt < 4; ++kt) {
      int krow = kt * 16 + lrow;
      int ksw = krow & 7;
      const unsigned short* Kr = Kst + krow * 64;
      bf16x8 k0 = *(const bf16x8*)(Kr + ((qd ^ ksw) << 3));
      bf16x8 k1 = *(const bf16x8*)(Kr + (((qd + 4) ^ ksw) << 3));
#pragma unroll
      for (int qs = 0; qs < 2; ++qs) {
        f32x4 z = (f32x4){0.f, 0.f, 0.f, 0.f};
        z = __builtin_amdgcn_mfma_f32_16x16x32_bf16(k0, qf[qs][0], z, 0, 0, 0);
        z = __builtin_amdgcn_mfma_f32_16x16x32_bf16(k1, qf[qs][1], z, 0, 0, 0);
        st[kt][qs] = z;
      }
    }

#pragma unroll
    for (int kt = 0; kt < 4; ++kt)
#pragma unroll
      for (int qs = 0; qs < 2; ++qs) {
        float p0 = __expf(st[kt][qs][0]);
        float p1 = __expf(st[kt][qs][1]);
        float p2 = __expf(st[kt][qs][2]);
        float p3 = __expf(st[kt][qs][3]);
        li[qs] += (p0 + p1) + (p2 + p3);
        uint2 pk;
        pk.x = (uint32_t)f2b(p0) | ((uint32_t)f2b(p1) << 16);
        pk.y = (uint32_t)f2b(p2) | ((uint32_t)f2b(p3) << 16);
        *(uint2*)(Pw + (qs * 16 + lrow) * PPAD + kt * 16 + qd * 4) = pk;
      }
    asm volatile("s_waitcnt lgkmcnt(0)" ::: "memory");

    bf16x8 ap[2][2];
#pragma unroll
    for (int qs = 0; qs < 2; ++qs)
#pragma unroll
      for (int kh = 0; kh < 2; ++kh)
        ap[qs][kh] = *(const bf16x8*)(Pw + (qs * 16 + lrow) * PPAD + kh * 32 + qd * 8);

#pragma unroll
    for (int ds = 0; ds < 4; ++ds) {
      int vrow = ds * 16 + lrow;
      int vsw = vrow & 7;
      const unsigned short* Vr = Vst + vrow * 64;
      bf16x8 v0 = *(const bf16x8*)(Vr + ((qd ^ vsw) << 3));
      bf16x8 v1 = *(const bf16x8*)(Vr + (((4 + qd) ^ vsw) << 3));
#pragma unroll
      for (int qs = 0; qs < 2; ++qs) {
        oacc[qs][ds] = __builtin_amdgcn_mfma_f32_16x16x32_bf16(ap[qs][0], v0, oacc[qs][ds], 0, 0, 0);
        oacc[qs][ds] = __builtin_amdgcn_mfma_f32_16x16x32_bf16(ap[qs][1], v1, oacc[qs][ds], 0, 0, 0);
      }
    }
  }

#pragma unroll
  for (int qs = 0; qs < 2; ++qs) {
    li[qs] += __shfl_xor(li[qs], 16);
    li[qs] += __shfl_xor(li[qs], 32);
  }

#pragma unroll
  for (int qs = 0; qs < 2; ++qs)
#pragma unroll
    for (int r = 0; r < 4; ++r) {
      float inv = 1.f / __shfl(li[qs], qd * 4 + r);
      int n = qw + qs * 16 + qd * 4 + r;
#pragma unroll
      for (int ds = 0; ds < 4; ++ds) {
        int dh = ds * 16 + lrow;
        o[((size_t)(b * SEQ + n)) * DIM + hh * DH + dh] = f2b(oacc[qs][ds][r] * inv);
      }
    }
}

extern "C" void kernel_launch(void* const* d_in, const int* in_sizes, int n_in,
                              void* d_out, int out_size, void* d_ws, size_t ws_size,
                              hipStream_t stream) {
  const float* x     = (const float*)d_in[0];
  const float* ln1_g = (const float*)d_in[1];
  const float* ln1_b = (const float*)d_in[2];
  const float* w_qkv = (const float*)d_in[3];
  const float* w_out = (const float*)d_in[4];
  const float* b_out = (const float*)d_in[5];
  const float* ln2_g = (const float*)d_in[6];
  const float* ln2_b = (const float*)d_in[7];
  const float* w1    = (const float*)d_in[8];
  const float* b1    = (const float*)d_in[9];
  const float* w2    = (const float*)d_in[10];
  const float* b2    = (const float*)d_in[11];

  char* ws = (char*)d_ws;
  unsigned short* wqkvT = (unsigned short*)(ws + 0);
  unsigned short* woutT = (unsigned short*)(ws + 3538944);
  unsigned short* w1T   = (unsigned short*)(ws + 4718592);
  unsigned short* w2T   = (unsigned short*)(ws + 9437184);
  float*          x2    = (float*)(ws + 14155776);
  unsigned short* h     = (unsigned short*)(ws + 39321600);
  char* big = ws + 51904512;
  unsigned short* Qb = (unsigned short*)(big);
  unsigned short* Kb = (unsigned short*)(big + 12582912);
  unsigned short* Vt = (unsigned short*)(big + 25165824);
  unsigned short* ob = (unsigned short*)(big + 37748736);
  unsigned short* am = (unsigned short*)(big);

  transpose_k<<<dim3(72, 24), 256, 0, stream>>>(w_qkv, wqkvT, 768, 2304);
  transpose_k<<<dim3(24, 24), 256, 0, stream>>>(w_out, woutT, 768, 768);
  transpose_k<<<dim3(96, 24), 256, 0, stream>>>(w1, w1T, 768, 3072);
  transpose_k<<<dim3(24, 96), 256, 0, stream>>>(w2, w2T, 3072, 768);

  ln_k<<<2048, 256, 0, stream>>>(x, ln1_g, ln1_b, h);
  gemm_k<0, 128><<<64 * 18, 256, 0, stream>>>(h, wqkvT, 2304, 768,
                                              nullptr, nullptr, nullptr, nullptr, Qb, Kb, Vt);
  attn_k<<<768, 256, 0, stream>>>(Qb, Kb, Vt, ob);
  gemm_k<1, 64><<<128 * 6, 256, 0, stream>>>(ob, woutT, 768, 768,
                                             b_out, x, x2, nullptr, nullptr, nullptr, nullptr);
  ln_k<<<2048, 256, 0, stream>>>(x2, ln2_g, ln2_b, h);
  gemm_k<2, 128><<<64 * 24, 256, 0, stream>>>(h, w1T, 3072, 768,
                                              b1, nullptr, nullptr, am, nullptr, nullptr, nullptr);
  gemm_k<1, 64><<<128 * 6, 256, 0, stream>>>(am, w2T, 768, 3072,
                                             b2, x2, (float*)d_out, nullptr, nullptr, nullptr, nullptr);
}